// Round 1
// baseline (940.381 us; speedup 1.0000x reference)
//
#include <hip/hip_runtime.h>

// LogSpaceSinkhorn: 64 matrices of 1024x1024 fp32.
// Matrix state is always ls0 - r_i - c_j, so we only ever compute potential
// vectors (r, c) via row/col logsumexp passes over the read-only input.

#define NROWS 1024
#define NCOLS 1024
#define NMAT 64

__device__ __forceinline__ float wave_max(float v) {
#pragma unroll
  for (int o = 32; o > 0; o >>= 1) v = fmaxf(v, __shfl_xor(v, o, 64));
  return v;
}
__device__ __forceinline__ float wave_sum(float v) {
#pragma unroll
  for (int o = 32; o > 0; o >>= 1) v += __shfl_xor(v, o, 64);
  return v;
}

// One wave per row. 256 threads = 4 rows per block.
// r[row] = LSE_j( x[row][j]*inv_tau - c[j] )
__global__ __launch_bounds__(256) void row_pass(
    const float* __restrict__ x, const float* __restrict__ c,
    float* __restrict__ r, const float* __restrict__ tau) {
  const float it = 1.0f / fmaxf(tau[0], 0.1f);
  const int row = blockIdx.x * 4 + (threadIdx.x >> 6);
  const int lane = threadIdx.x & 63;
  const int b = row >> 10;  // matrix index
  const float4* xb = (const float4*)(x + (size_t)row * NCOLS);
  const float4* cb = (const float4*)(c + (size_t)b * NCOLS);

  float4 t[4];
  float m = -3.0e38f;
#pragma unroll
  for (int k = 0; k < 4; ++k) {
    float4 v = xb[lane + 64 * k];
    float4 cv = cb[lane + 64 * k];
    t[k].x = v.x * it - cv.x;
    t[k].y = v.y * it - cv.y;
    t[k].z = v.z * it - cv.z;
    t[k].w = v.w * it - cv.w;
    m = fmaxf(m, fmaxf(fmaxf(t[k].x, t[k].y), fmaxf(t[k].z, t[k].w)));
  }
  m = wave_max(m);
  float s = 0.0f;
#pragma unroll
  for (int k = 0; k < 4; ++k) {
    s += __expf(t[k].x - m) + __expf(t[k].y - m) + __expf(t[k].z - m) +
         __expf(t[k].w - m);
  }
  s = wave_sum(s);
  if (lane == 0) r[row] = m + __logf(s);
}

// Block = 1024 threads; block covers a 256-column stripe across all 1024 rows
// of one matrix. grid = 64 matrices * 4 stripes = 256 blocks.
// Thread (rg = tid>>6 in [0,16), colq = tid&63) handles 4 consecutive columns
// (one float4) over 64 rows; LDS combine across the 16 row-groups.
// FUSE=0: cout[j] = LSE_i( x[i][j]*it - r[i] )
// FUSE=1: e[j] = LSE_i(...) then out[i][j] = exp(x*it - r[i] - 0.5*(cin[j]+e[j]))
template <int FUSE>
__global__ __launch_bounds__(1024) void col_pass(
    const float* __restrict__ x, const float* __restrict__ r,
    const float* __restrict__ cin, float* __restrict__ cout,
    float* __restrict__ out, const float* __restrict__ tau) {
  const float it = 1.0f / fmaxf(tau[0], 0.1f);
  const int mat = blockIdx.x >> 2;
  const int cb = blockIdx.x & 3;
  const int colq = threadIdx.x & 63;   // float4 column index within stripe
  const int rg = threadIdx.x >> 6;     // row group 0..15 (64 rows each)
  const int col4 = cb * 64 + colq;     // float4 index within a row (0..255)
  const float* xb = x + (size_t)mat * NROWS * NCOLS;
  const float* rb = r + mat * NROWS;

  float4 mx = make_float4(-3.0e38f, -3.0e38f, -3.0e38f, -3.0e38f);
  float4 s = make_float4(0.f, 0.f, 0.f, 0.f);
  for (int rr = 0; rr < 64; ++rr) {
    const int row = rg * 64 + rr;
    float4 v = ((const float4*)(xb + (size_t)row * NCOLS))[col4];
    const float ri = rb[row];
    float4 t;
    t.x = v.x * it - ri;
    t.y = v.y * it - ri;
    t.z = v.z * it - ri;
    t.w = v.w * it - ri;
    float4 nm;
    nm.x = fmaxf(mx.x, t.x);
    nm.y = fmaxf(mx.y, t.y);
    nm.z = fmaxf(mx.z, t.z);
    nm.w = fmaxf(mx.w, t.w);
    s.x = s.x * __expf(mx.x - nm.x) + __expf(t.x - nm.x);
    s.y = s.y * __expf(mx.y - nm.y) + __expf(t.y - nm.y);
    s.z = s.z * __expf(mx.z - nm.z) + __expf(t.z - nm.z);
    s.w = s.w * __expf(mx.w - nm.w) + __expf(t.w - nm.w);
    mx = nm;
  }

  __shared__ float4 sm[16][64];
  __shared__ float4 ss[16][64];
  __shared__ float4 lse_s[64];
  sm[rg][colq] = mx;
  ss[rg][colq] = s;
  __syncthreads();
  if (threadIdx.x < 64) {
    float4 M = sm[0][colq];
    float4 S = ss[0][colq];
#pragma unroll
    for (int g = 1; g < 16; ++g) {
      float4 m2 = sm[g][colq];
      float4 s2 = ss[g][colq];
      float4 nm;
      nm.x = fmaxf(M.x, m2.x);
      nm.y = fmaxf(M.y, m2.y);
      nm.z = fmaxf(M.z, m2.z);
      nm.w = fmaxf(M.w, m2.w);
      S.x = S.x * __expf(M.x - nm.x) + s2.x * __expf(m2.x - nm.x);
      S.y = S.y * __expf(M.y - nm.y) + s2.y * __expf(m2.y - nm.y);
      S.z = S.z * __expf(M.z - nm.z) + s2.z * __expf(m2.z - nm.z);
      S.w = S.w * __expf(M.w - nm.w) + s2.w * __expf(m2.w - nm.w);
      M = nm;
    }
    float4 L;
    L.x = M.x + __logf(S.x);
    L.y = M.y + __logf(S.y);
    L.z = M.z + __logf(S.z);
    L.w = M.w + __logf(S.w);
    if (FUSE) {
      lse_s[colq] = L;
    } else {
      ((float4*)(cout + mat * NCOLS))[col4] = L;
    }
  }
  if (FUSE) {
    __syncthreads();
    float4 e = lse_s[colq];
    float4 cj = ((const float4*)(cin + mat * NCOLS))[col4];
    float4 h;
    h.x = 0.5f * (e.x + cj.x);
    h.y = 0.5f * (e.y + cj.y);
    h.z = 0.5f * (e.z + cj.z);
    h.w = 0.5f * (e.w + cj.w);
    for (int rr = 0; rr < 64; ++rr) {
      const int row = rg * 64 + rr;
      float4 v = ((const float4*)(xb + (size_t)row * NCOLS))[col4];
      const float ri = rb[row];
      float4 o;
      o.x = __expf(v.x * it - ri - h.x);
      o.y = __expf(v.y * it - ri - h.y);
      o.z = __expf(v.z * it - ri - h.z);
      o.w = __expf(v.w * it - ri - h.w);
      ((float4*)(out + (size_t)mat * NROWS * NCOLS + (size_t)row * NCOLS))[col4] = o;
    }
  }
}

extern "C" void kernel_launch(void* const* d_in, const int* in_sizes, int n_in,
                              void* d_out, int out_size, void* d_ws,
                              size_t ws_size, hipStream_t stream) {
  const float* x = (const float*)d_in[0];
  const float* tau = (const float*)d_in[1];
  float* out = (float*)d_out;

  float* r = (float*)d_ws;              // 64*1024 floats
  float* c = r + NMAT * NROWS;          // 64*1024 floats

  hipMemsetAsync(c, 0, NMAT * NCOLS * sizeof(float), stream);

  const int row_grid = NMAT * NROWS / 4;  // 16384 blocks, wave per row
  const int col_grid = NMAT * 4;          // 256 blocks

  for (int i = 0; i < 5; ++i) {
    row_pass<<<row_grid, 256, 0, stream>>>(x, c, r, tau);
    col_pass<0><<<col_grid, 1024, 0, stream>>>(x, r, nullptr, c, nullptr, tau);
  }
  // final row normalize, then fused col-LSE + symmetric output
  row_pass<<<row_grid, 256, 0, stream>>>(x, c, r, tau);
  col_pass<1><<<col_grid, 1024, 0, stream>>>(x, r, c, nullptr, out, tau);
}

// Round 2
// 734.004 us; speedup vs baseline: 1.2812x; 1.2812x over previous
//
#include <hip/hip_runtime.h>
#include <hip/hip_fp16.h>

// LogSpaceSinkhorn: 64 matrices of 1024x1024 fp32.
// Potentials-only formulation: state is always t - r_i - c_j with
// t = x/tau cached ONCE as fp16 (halves all re-read traffic).
// Max-free LSE: after row norm all elements <= 0, sums bounded; fp32 sums
// never overflow (args <= ~12.4, sums <= ~2.5e8).

#define NROWS 1024
#define NCOLS 1024
#define NMAT 64
#define MATELEMS (NROWS * NCOLS)

struct H8 { __half2 h[4]; };  // 16 bytes = 8 halves

__device__ __forceinline__ float wave_sum(float v) {
#pragma unroll
  for (int o = 32; o > 0; o >>= 1) v += __shfl_xor(v, o, 64);
  return v;
}

// Pass 1: t = x*it stored as fp16; r[row] = log sum_j exp(t).
// One wave per row, 4 rows per 256-thread block.
__global__ __launch_bounds__(256) void convert_row(
    const float* __restrict__ x, __half* __restrict__ t,
    float* __restrict__ r, const float* __restrict__ tau) {
  const float it = 1.0f / fmaxf(tau[0], 0.1f);
  const int row = blockIdx.x * 4 + (threadIdx.x >> 6);
  const int lane = threadIdx.x & 63;
  const float4* xr = (const float4*)(x + (size_t)row * NCOLS);
  H8* tr = (H8*)(t + (size_t)row * NCOLS);
  float s = 0.0f;
#pragma unroll
  for (int k = 0; k < 2; ++k) {
    const int f4 = k * 128 + lane * 2;  // float4 index in row
    float4 a = xr[f4];
    float4 b = xr[f4 + 1];
    a.x *= it; a.y *= it; a.z *= it; a.w *= it;
    b.x *= it; b.y *= it; b.z *= it; b.w *= it;
    H8 o;
    o.h[0] = __floats2half2_rn(a.x, a.y);
    o.h[1] = __floats2half2_rn(a.z, a.w);
    o.h[2] = __floats2half2_rn(b.x, b.y);
    o.h[3] = __floats2half2_rn(b.z, b.w);
    tr[k * 64 + lane] = o;
    s += __expf(a.x) + __expf(a.y) + __expf(a.z) + __expf(a.w) +
         __expf(b.x) + __expf(b.y) + __expf(b.z) + __expf(b.w);
  }
  s = wave_sum(s);
  if (lane == 0) r[row] = __logf(s);
}

// r[row] = log sum_j exp(t[row][j] - c[j]). One wave per row.
__global__ __launch_bounds__(256) void row_pass(
    const __half* __restrict__ t, const float* __restrict__ c,
    float* __restrict__ r) {
  const int row = blockIdx.x * 4 + (threadIdx.x >> 6);
  const int lane = threadIdx.x & 63;
  const int mat = row >> 10;
  const H8* tr = (const H8*)(t + (size_t)row * NCOLS);
  const float4* cm = (const float4*)(c + mat * NCOLS);
  float s = 0.0f;
#pragma unroll
  for (int k = 0; k < 2; ++k) {
    H8 v = tr[k * 64 + lane];
    const int f4 = k * 128 + lane * 2;
    float4 c0 = cm[f4];
    float4 c1 = cm[f4 + 1];
    float2 f0 = __half22float2(v.h[0]);
    float2 f1 = __half22float2(v.h[1]);
    float2 f2 = __half22float2(v.h[2]);
    float2 f3 = __half22float2(v.h[3]);
    s += __expf(f0.x - c0.x) + __expf(f0.y - c0.y) +
         __expf(f1.x - c0.z) + __expf(f1.y - c0.w) +
         __expf(f2.x - c1.x) + __expf(f2.y - c1.y) +
         __expf(f3.x - c1.z) + __expf(f3.y - c1.w);
  }
  s = wave_sum(s);
  if (lane == 0) r[row] = __logf(s);
}

// Col pass: 8 blocks per matrix, each covers a 128-col stripe x 1024 rows.
// 256 threads: colh = tid&15 owns 8 consecutive cols (one 16B fp16 load),
// rg = tid>>4 sweeps 64 rows. LDS add-combine across the 16 row groups.
// FUSE=0: cout[j] = log sum_i exp(t - r_i)
// FUSE=1: e[j] = log sum_i exp(t - r_i);
//         out[i][j] = exp(t - r_i - 0.5*(cin[j] + e[j]))
template <int FUSE>
__global__ __launch_bounds__(256) void col_pass(
    const __half* __restrict__ t, const float* __restrict__ r,
    const float* __restrict__ cin, float* __restrict__ cout,
    float* __restrict__ out) {
  const int mat = blockIdx.x >> 3;
  const int cb = blockIdx.x & 7;
  const int colh = threadIdx.x & 15;  // H8 group within the 128-col stripe
  const int rg = threadIdx.x >> 4;    // row group 0..15 (64 rows each)
  const int h8idx = cb * 16 + colh;   // H8 index within a full row [0,128)
  const __half* tb = t + (size_t)mat * MATELEMS;
  const float* rb = r + mat * NROWS;

  float s[8];
#pragma unroll
  for (int j = 0; j < 8; ++j) s[j] = 0.0f;

  for (int rr = 0; rr < 64; ++rr) {
    const int row = rg * 64 + rr;
    H8 v = ((const H8*)(tb + (size_t)row * NCOLS))[h8idx];
    const float ri = rb[row];
#pragma unroll
    for (int j = 0; j < 4; ++j) {
      float2 f = __half22float2(v.h[j]);
      s[2 * j] += __expf(f.x - ri);
      s[2 * j + 1] += __expf(f.y - ri);
    }
  }

  __shared__ float ls[16][128];
  __shared__ float hs[128];
#pragma unroll
  for (int j = 0; j < 8; ++j) ls[rg][colh * 8 + j] = s[j];
  __syncthreads();

  if (threadIdx.x < 128) {
    float acc = 0.0f;
#pragma unroll
    for (int g = 0; g < 16; ++g) acc += ls[g][threadIdx.x];
    const float lse = __logf(acc);
    if (FUSE) {
      hs[threadIdx.x] = 0.5f * (lse + cin[mat * NCOLS + cb * 128 + threadIdx.x]);
    } else {
      cout[mat * NCOLS + cb * 128 + threadIdx.x] = lse;
    }
  }

  if (FUSE) {
    __syncthreads();
    float h[8];
#pragma unroll
    for (int j = 0; j < 8; ++j) h[j] = hs[colh * 8 + j];
    float* ob = out + (size_t)mat * MATELEMS;
    for (int rr = 0; rr < 64; ++rr) {
      const int row = rg * 64 + rr;
      H8 v = ((const H8*)(tb + (size_t)row * NCOLS))[h8idx];
      const float ri = rb[row];
      float4 o0, o1;
      float2 f0 = __half22float2(v.h[0]);
      float2 f1 = __half22float2(v.h[1]);
      float2 f2 = __half22float2(v.h[2]);
      float2 f3 = __half22float2(v.h[3]);
      o0.x = __expf(f0.x - ri - h[0]);
      o0.y = __expf(f0.y - ri - h[1]);
      o0.z = __expf(f1.x - ri - h[2]);
      o0.w = __expf(f1.y - ri - h[3]);
      o1.x = __expf(f2.x - ri - h[4]);
      o1.y = __expf(f2.y - ri - h[5]);
      o1.z = __expf(f3.x - ri - h[6]);
      o1.w = __expf(f3.y - ri - h[7]);
      float4* op = (float4*)(ob + (size_t)row * NCOLS) + h8idx * 2;
      op[0] = o0;
      op[1] = o1;
    }
  }
}

extern "C" void kernel_launch(void* const* d_in, const int* in_sizes, int n_in,
                              void* d_out, int out_size, void* d_ws,
                              size_t ws_size, hipStream_t stream) {
  const float* x = (const float*)d_in[0];
  const float* tau = (const float*)d_in[1];
  float* out = (float*)d_out;

  __half* t = (__half*)d_ws;                        // 128 MB fp16 matrix cache
  float* r = (float*)((char*)d_ws + (size_t)NMAT * MATELEMS * sizeof(__half));
  float* c = r + NMAT * NROWS;

  const int row_grid = NMAT * NROWS / 4;  // 16384
  const int col_grid = NMAT * 8;          // 512

  convert_row<<<row_grid, 256, 0, stream>>>(x, t, r, tau);  // R1
  for (int i = 0; i < 5; ++i) {
    col_pass<0><<<col_grid, 256, 0, stream>>>(t, r, nullptr, c, nullptr);  // C_i
    row_pass<<<row_grid, 256, 0, stream>>>(t, c, r);                       // R_{i+1}
  }
  // fused: e = col LSE of (t - R6); out = exp(t - R6 - 0.5*(C5 + e))
  col_pass<1><<<col_grid, 256, 0, stream>>>(t, r, c, nullptr, out);
}